// Round 3
// baseline (48.792 us; speedup 1.0000x reference)
//
#include <hip/hip_runtime.h>

// LTI all-pass: cascade of 8 second-order all-pass sections in DF2T form.
//   per section: y = B2*x + s1 ; s1' = B1*(x-y) + s2 ; s2' = x - B2*y
// Cascade = z^-16 A(1/z)/A(z) = B(z)/A(z) with b = a[::-1] (the reference).
//
// Overlap-and-discard: mag <= sigmoid(1.3608)*0.99 = 0.7881 (hard bound from
// setup), warm-up 64 -> transient ~2.4e-7, far below threshold.
//
// Round-3 structure: block stages its contiguous input span into LDS with
// coalesced float4 loads (fixes the 256B-stride scatter that round 1/2
// choked on), threads read private windows from LDS (+1-per-64 padding ->
// 2-way banks = free). 65.3 KB LDS -> 2 blocks/CU -> 4 waves/SIMD.

#define NROOTS 8
#define BATCH  32
#define TLEN   262144
#define CHUNK  64
#define WARM   64
#define BLOCK  256
#define SPAN   (BLOCK * CHUNK)        // 16384 samples per block
#define CPR    (TLEN / CHUNK)         // 4096 chunks per row
#define BPR    (CPR / BLOCK)          // 16 blocks per row

#define LDS_N  (SPAN + WARM + (SPAN + WARM) / 64 + 4)   // padded floats

__global__ __launch_bounds__(256, 4) void allpass_kernel(
    const float* __restrict__ x,
    const float* __restrict__ mag_logits,
    const float* __restrict__ cos_logits,
    float* __restrict__ y)
{
    __shared__ float xs[LDS_N];

    const int tid  = threadIdx.x;
    const int brow = blockIdx.x >> 4;      // / BPR
    const int bcol = blockIdx.x & (BPR - 1);

    const int off = (bcol == 0) ? 0 : WARM;          // LDS index of block span start
    const size_t gbase = (size_t)brow * TLEN + (size_t)bcol * SPAN - off;
    const int nstage = SPAN + off;                   // floats to stage
    const int n4 = nstage >> 2;

    // ---- coalesced global -> LDS staging (padded: idx = t + t/64) ----
    const float4* g4 = reinterpret_cast<const float4*>(x + gbase);
    for (int k = tid; k < n4; k += BLOCK) {
        float4 v = g4[k];
        int t = k << 2;
        int idx = t + (t >> 6);        // t%4==0 => no 64-boundary inside the 4
        xs[idx]     = v.x;
        xs[idx + 1] = v.y;
        xs[idx + 2] = v.z;
        xs[idx + 3] = v.w;
    }

    // ---- coefficients: one transcendental pair per lane, broadcast ----
    const int lane = tid & 63;
    float ml = mag_logits[lane & 7];
    float cl = cos_logits[lane & 7];
    float m  = 0.99f / (1.0f + expf(-ml));
    float cc = tanhf(cl);
    float myb1 = -2.0f * m * cc;
    float myb2 = m * m;
    float B1[NROOTS], B2[NROOTS], s1[NROOTS], s2[NROOTS];
#pragma unroll
    for (int s = 0; s < NROOTS; ++s) {
        B1[s] = __shfl(myb1, s);
        B2[s] = __shfl(myb2, s);
        s1[s] = 0.0f;
        s2[s] = 0.0f;
    }

    __syncthreads();

    auto step = [&](float v) -> float {
#pragma unroll
        for (int s = 0; s < NROOTS; ++s) {
            float o = fmaf(B2[s], v, s1[s]);
            s1[s] = fmaf(B1[s], v - o, s2[s]);
            s2[s] = fmaf(-B2[s], o, v);
            v = o;
        }
        return v;
    };

    // thread's first LDS sample index (start of its warm region)
    const int warm = (bcol == 0 && tid == 0) ? 0 : WARM;
    int t = off + tid * CHUNK - warm;

    // ---- warm-up (discarded). 16-sample tiles: t%16==0 => t>>6 constant in tile
    for (int w = 0; w < warm; w += 16) {
        int base = t + (t >> 6);
#pragma unroll
        for (int j = 0; j < 16; ++j)
            step(xs[base + j]);
        t += 16;
    }

    // ---- output phase ----
    float* po = y + (size_t)brow * TLEN + (size_t)bcol * SPAN + (size_t)tid * CHUNK;
    for (int w = 0; w < CHUNK; w += 16) {
        int base = t + (t >> 6);
        float4 o0, o1, o2, o3;
        o0.x = step(xs[base + 0]);  o0.y = step(xs[base + 1]);
        o0.z = step(xs[base + 2]);  o0.w = step(xs[base + 3]);
        o1.x = step(xs[base + 4]);  o1.y = step(xs[base + 5]);
        o1.z = step(xs[base + 6]);  o1.w = step(xs[base + 7]);
        o2.x = step(xs[base + 8]);  o2.y = step(xs[base + 9]);
        o2.z = step(xs[base + 10]); o2.w = step(xs[base + 11]);
        o3.x = step(xs[base + 12]); o3.y = step(xs[base + 13]);
        o3.z = step(xs[base + 14]); o3.w = step(xs[base + 15]);
        float4* p4 = reinterpret_cast<float4*>(po + w);
        p4[0] = o0; p4[1] = o1; p4[2] = o2; p4[3] = o3;
        t += 16;
    }
}

extern "C" void kernel_launch(void* const* d_in, const int* in_sizes, int n_in,
                              void* d_out, int out_size, void* d_ws, size_t ws_size,
                              hipStream_t stream) {
    const float* ex = (const float*)d_in[0];
    const float* ml = (const float*)d_in[1];
    const float* cl = (const float*)d_in[2];
    float* yo = (float*)d_out;

    allpass_kernel<<<BATCH * BPR, BLOCK, 0, stream>>>(ex, ml, cl, yo);
}

// Round 4
// 28.729 us; speedup vs baseline: 1.6984x; 1.6984x over previous
//
#include <hip/hip_runtime.h>

// LTI all-pass: cascade of 8 second-order all-pass sections (DF2T):
//   y = B2*x + s1 ; s1' = B1*(x-y) + s2 ; s2' = x - B2*y
// Cascade = z^-16 A(1/z)/A(z) = B(z)/A(z) with b = a[::-1] (the reference).
//
// Overlap-and-discard: mag <= sigmoid(1.3608)*0.99 = 0.7881 (hard bound from
// setup), warm-up 64 -> transient ~2.4e-7 << 0.112 threshold.
//
// Round-4 structure: 1-wave blocks (64 threads), each owning a 4096-sample
// window + 64 warm samples staged in 16.5KB LDS (stride-65 padding -> LDS
// scalar reads/writes are bank-conflict-free). Outputs overwrite the LDS
// window in place (warm reads all precede output writes in wave program
// order), then one coalesced float4 copy-out. Zero scattered global access;
// ~8-9 independent 1-wave blocks resident per CU for latency hiding.

#define NROOTS 8
#define BATCH  32
#define TLEN   262144
#define CHUNK  64
#define WARM   64
#define BLOCK  64
#define WIN    (BLOCK * CHUNK)          // 4096 output samples per block
#define PIECE  (WIN + WARM)             // 4160 staged samples
#define BPR    (TLEN / WIN)             // 64 blocks per row
#define LDSF   (PIECE + PIECE / 64 + 8) // 4233 floats = 16.5KB

__global__ __launch_bounds__(64) void allpass_kernel(
    const float* __restrict__ x,
    const float* __restrict__ mag_logits,
    const float* __restrict__ cos_logits,
    float* __restrict__ y)
{
    __shared__ float xs[LDSF];

    const int lane = threadIdx.x;           // 0..63
    const int brow = blockIdx.x >> 6;       // / BPR
    const int bcol = blockIdx.x & (BPR - 1);
    const size_t wstart = (size_t)brow * TLEN + (size_t)bcol * WIN;

    // ---- stage: global (coalesced float4) -> LDS (padded scalar) ----
    // piece float f  <->  global sample wstart - WARM + f ; for bcol==0 the
    // first WARM floats are left unstaged (lane 0 skips its warm-up instead).
    const bool first = (bcol == 0);
    const int  start = first ? WARM : 0;
    const float* gsrc = x + wstart - (first ? 0 : WARM);
    const int  nst = PIECE - start;         // 4096 or 4160

    for (int k = 0; k < 17; ++k) {
        int t = 256 * k + 4 * lane;
        if (t < nst) {
            float4 v = *reinterpret_cast<const float4*>(gsrc + t);
            int f = start + t;              // f%64 in {0,...,60}: no pad crossing
            int idx = f + (f >> 6);
            xs[idx] = v.x; xs[idx + 1] = v.y; xs[idx + 2] = v.z; xs[idx + 3] = v.w;
        }
    }

    // ---- coefficients: one transcendental pair per lane, broadcast ----
    float mlv = mag_logits[lane & 7];
    float clv = cos_logits[lane & 7];
    float mm  = 0.99f / (1.0f + expf(-mlv));
    float cc  = tanhf(clv);
    float b1v = -2.0f * mm * cc;
    float b2v = mm * mm;
    float B1[NROOTS], B2[NROOTS], s1[NROOTS], s2[NROOTS];
#pragma unroll
    for (int s = 0; s < NROOTS; ++s) {
        B1[s] = __shfl(b1v, s);
        B2[s] = __shfl(b2v, s);
        s1[s] = 0.0f; s2[s] = 0.0f;
    }

    __syncthreads();   // 1-wave block: ~free

    auto step = [&](float v) -> float {
#pragma unroll
        for (int s = 0; s < NROOTS; ++s) {
            float o = fmaf(B2[s], v, s1[s]);
            s1[s] = fmaf(B1[s], v - o, s2[s]);
            s2[s] = fmaf(-B2[s], o, v);
            v = o;
        }
        return v;
    };

    // lane l: warm = piece floats [64l, 64l+64) (= lane l-1's chunk),
    //         out  = piece floats [64l+64, 64l+128), written back in place.
    const bool dowarm = !(first && lane == 0);
    if (dowarm) {
        for (int w = 0; w < 4; ++w) {
            int f = 64 * lane + 16 * w;
            int idx = f + (f >> 6);
#pragma unroll
            for (int j = 0; j < 16; ++j)
                step(xs[idx + j]);
        }
    }
    for (int w = 0; w < 4; ++w) {
        int f = 64 * lane + 64 + 16 * w;
        int idx = f + (f >> 6);
        float o[16];
#pragma unroll
        for (int j = 0; j < 16; ++j)
            o[j] = step(xs[idx + j]);
#pragma unroll
        for (int j = 0; j < 16; ++j)
            xs[idx + j] = o[j];
    }

    __syncthreads();   // 1-wave block: ~free

    // ---- copy-out: LDS -> global, coalesced float4 ----
    float* gdst = y + wstart;
    for (int k = 0; k < 16; ++k) {
        int t = 256 * k + 4 * lane;         // 0..4092
        int f = t + WARM;
        int idx = f + (f >> 6);
        float4 v;
        v.x = xs[idx];     v.y = xs[idx + 1];
        v.z = xs[idx + 2]; v.w = xs[idx + 3];
        *reinterpret_cast<float4*>(gdst + t) = v;
    }
}

extern "C" void kernel_launch(void* const* d_in, const int* in_sizes, int n_in,
                              void* d_out, int out_size, void* d_ws, size_t ws_size,
                              hipStream_t stream) {
    const float* ex = (const float*)d_in[0];
    const float* ml = (const float*)d_in[1];
    const float* cl = (const float*)d_in[2];
    float* yo = (float*)d_out;

    allpass_kernel<<<BATCH * BPR, BLOCK, 0, stream>>>(ex, ml, cl, yo);
}